// Round 5
// baseline (597.954 us; speedup 1.0000x reference)
//
#include <hip/hip_runtime.h>
#include <math.h>

// ---- problem constants ----
#define BB 32
#define LL 128
#define HSZ 512
#define PP 12
#define MM 1024
#define VV 50000
#define DD 128
#define CLEN 16
#define NTOT 4096           // B*L
#define LISTCAP 512

// fused kernel config
#define GRIDN 512           // 2 blocks/CU * 256 CU -> all co-resident
#define RPB 8               // rows per block (NTOT/GRIDN)
#define CT 64
#define RT 64
#define BK 64

// output offsets (floats)
#define OFF_WORD  0
#define OFF_CHAR  4096
#define OFF_PSR   69632
#define OFF_ATK   593920
#define OFF_OBFM  1118208
#define OFF_CPYM  1122304
#define OFF_PRIM  1126400
#define OFF_CLOSS 1130496
#define OFF_ELOSS 1130497

// ws layout: ints [0]=barrier [1]=ticket [2..13]=cnt [14]=nr ; floats [32..43]=ent [44]=closs
// ints [64..6207]=rowlist ; floats [8192..16383]=scbuf(fallback) ; floats [16384..]=logits
#define WSI_BAR 0
#define WSI_TKT 1
#define WSI_CNT 2
#define WSI_NR  14
#define WSF_ENT 32
#define WSF_CLS 44
#define WSI_ROWLIST 64
#define WS_SC_OFF     8192
#define WS_LOGITS_OFF 16384

// ---- CR-f32 transcendentals via double libm (bit-critical paths only) ----
__device__ __forceinline__ float EXP32(float x){ return (float)exp((double)x); }
__device__ __forceinline__ float LOG32(float x){ return (float)log((double)x); }

// ---- JAX threefry2x32 (20 rounds) — verified vs known-answer vector ----
__device__ __forceinline__ unsigned rotl32(unsigned x, int r){ return (x<<r)|(x>>(32-r)); }
__device__ __forceinline__ void tf2x32(unsigned k0, unsigned k1, unsigned x0, unsigned x1,
                                       unsigned &o0, unsigned &o1){
  unsigned ks2 = k0 ^ k1 ^ 0x1BD11BDAu;
  x0 += k0; x1 += k1;
  x0+=x1; x1=rotl32(x1,13); x1^=x0;
  x0+=x1; x1=rotl32(x1,15); x1^=x0;
  x0+=x1; x1=rotl32(x1,26); x1^=x0;
  x0+=x1; x1=rotl32(x1, 6); x1^=x0;
  x0+=k1; x1+=ks2+1u;
  x0+=x1; x1=rotl32(x1,17); x1^=x0;
  x0+=x1; x1=rotl32(x1,29); x1^=x0;
  x0+=x1; x1=rotl32(x1,16); x1^=x0;
  x0+=x1; x1=rotl32(x1,24); x1^=x0;
  x0+=ks2; x1+=k0+2u;
  x0+=x1; x1=rotl32(x1,13); x1^=x0;
  x0+=x1; x1=rotl32(x1,15); x1^=x0;
  x0+=x1; x1=rotl32(x1,26); x1^=x0;
  x0+=x1; x1=rotl32(x1, 6); x1^=x0;
  x0+=k0; x1+=k1+3u;
  x0+=x1; x1=rotl32(x1,17); x1^=x0;
  x0+=x1; x1=rotl32(x1,29); x1^=x0;
  x0+=x1; x1=rotl32(x1,16); x1^=x0;
  x0+=x1; x1=rotl32(x1,24); x1^=x0;
  x0+=k1; x1+=ks2+4u;
  x0+=x1; x1=rotl32(x1,13); x1^=x0;
  x0+=x1; x1=rotl32(x1,15); x1^=x0;
  x0+=x1; x1=rotl32(x1,26); x1^=x0;
  x0+=x1; x1=rotl32(x1, 6); x1^=x0;
  x0+=ks2; x1+=k0+5u;
  o0=x0; o1=x1;
}

// jax_threefry_partitionable=True random_bits: count (0,e), output o0^o1
__device__ __forceinline__ unsigned tf_bits32(unsigned k0, unsigned k1, unsigned e){
  unsigned o0, o1; tf2x32(k0, k1, 0u, e, o0, o1); return o0 ^ o1;
}

__device__ __forceinline__ float bits_to_unif(unsigned bits){
  const float lo = 1e-6f;
  const float hi = (float)(1.0 - 1e-6);
  const float span = hi - lo;
  unsigned fb = (bits >> 9) | 0x3f800000u;
  float f = __fsub_rn(__uint_as_float(fb), 1.0f);
  float r = __fadd_rn(__fmul_rn(f, span), lo);
  return fmaxf(lo, r);
}

// exact (CR) gumbel — cpy gate only
__device__ __forceinline__ float gumbel_exact(unsigned bits){
  float u = bits_to_unif(bits);
  float v = -LOG32(u);
  return -LOG32(v);
}
// fast (ocml f32, ~1 ulp relative) gumbel — finalize argmax path
__device__ __forceinline__ float gumbel_fast(unsigned bits){
  float u = bits_to_unif(bits);
  float v = -logf(u);
  return -logf(v);
}

// ---- device-scope grid barrier (all GRIDN blocks co-resident by construction)
__device__ __forceinline__ void gbar(int* bar, int target){
  __syncthreads();
  if (threadIdx.x == 0){
    __threadfence();
    atomicAdd(bar, 1);
    int it = 0;
    while (atomicAdd(bar, 0) < target && it < (1<<22)){ ++it; __builtin_amdgcn_s_sleep(2); }
    __threadfence();
  }
  __syncthreads();
}

// =====================  FUSED PERSISTENT KERNEL  =====================
__global__ __launch_bounds__(256, 2)
void fused_kernel(const float* __restrict__ ctx, const float* __restrict__ dec_W,
                  const float* __restrict__ dec_b, const float* __restrict__ psr_w,
                  const float* __restrict__ atk_w, const float* __restrict__ cW1,
                  const float* __restrict__ cb1, const float* __restrict__ cW2,
                  const float* __restrict__ cb2, const int* __restrict__ inp_word,
                  const int* __restrict__ inp_pos, const int* __restrict__ inp_mask,
                  const int* __restrict__ words, const int* __restrict__ lut,
                  float* __restrict__ out, int* __restrict__ wsI, float* __restrict__ wsF,
                  float* __restrict__ lg0, float* __restrict__ lg1, int KS)
{
  const int bid = blockIdx.x;
  const int t = threadIdx.x;
  const int wid = t >> 6, lane = t & 63;

  __shared__ float As[BK][RT+4];     // [k][row]
  __shared__ float Bs[BK][CT+4];     // [k][col]
  __shared__ int   rid_s[RT];
  __shared__ int   s_unit;
  __shared__ float pcr_s[RPB][2];
  __shared__ float sc_s[RPB][2];
  __shared__ float  sMax[4];
  __shared__ double sSum[4];
  __shared__ double sEnt[4];
  __shared__ float  sBv[4];
  __shared__ int    sBi[4];
  __shared__ int    s_si;

  // ================= PHASE 1: build buckets + cpy MLP/gate (rows bid*8..+7)
  if (t < RPB){
    int n = bid*RPB + t;
    int p = inp_pos[n];
    if (p < PP){
      int slot = atomicAdd(&wsI[WSI_CNT + p], 1);
      if (slot < LISTCAP) wsI[WSI_ROWLIST + p*LISTCAP + slot] = n;
    }
    if (inp_mask[n] != 0 && (n & (LL-1)) != 0) atomicAdd(&wsI[WSI_NR], 1);
  }

  // MLP: wave w handles rows w and w+4; lane o computes h[o]; butterfly for pc
  #pragma unroll
  for (int rr = 0; rr < 2; ++rr){
    const int i = wid + rr*4;
    const int n = bid*RPB + i;
    const float* ctxn = ctx + (size_t)n*HSZ;
    const float* w1o  = cW1 + lane;
    double s0=0.0, s1=0.0, s2=0.0, s3=0.0;
    for (int kk = 0; kk < 128; ++kk){
      s0 += (double)ctxn[kk]       * (double)w1o[(size_t)(kk)*64];
      s1 += (double)ctxn[128+kk]   * (double)w1o[(size_t)(128+kk)*64];
      s2 += (double)ctxn[256+kk]   * (double)w1o[(size_t)(256+kk)*64];
      s3 += (double)ctxn[384+kk]   * (double)w1o[(size_t)(384+kk)*64];
    }
    double s = ((s0 + s1) + s2) + s3;
    float hv = __fadd_rn((float)s, cb1[lane]);
    hv = hv > 0.f ? hv : 0.f;
    double hd = (double)hv;
    double p0 = hd * (double)cW2[2*lane + 0];
    double p1 = hd * (double)cW2[2*lane + 1];
    #pragma unroll
    for (int off = 32; off > 0; off >>= 1){
      p0 += __shfl_xor(p0, off);
      p1 += __shfl_xor(p1, off);
    }
    if (lane == 0){ pcr_s[i][0] = (float)p0; pcr_s[i][1] = (float)p1; }
  }
  __syncthreads();

  // gates: 8 rows in parallel on lanes 0..7 of wave 0 (CR double-libm chain —
  // bit-identical to r2-r4: decides c in {1, 1-2^-24} -> cpy_mask)
  if (t < RPB){
    const int n = bid*RPB + t;
    const int pos = inp_pos[n];
    const int msk = inp_mask[n];
    const bool ispri = (pos < 4);
    float pc0 = __fadd_rn(pcr_s[t][0], cb2[0]);
    float pc1 = __fadd_rn(pcr_s[t][1], cb2[1]);
    float m2  = fmaxf(pc0, pc1);
    float s0  = __fsub_rn(pc0, m2), s1 = __fsub_rn(pc1, m2);
    float se  = __fadd_rn(EXP32(s0), EXP32(s1));
    float lse = LOG32(se);
    float q0  = __fsub_rn(s0, lse), q1 = __fsub_rn(s1, lse);
    if (ispri){ q0 = 0.0f; q1 = 1.0f; }

    unsigned k90, k91; tf2x32(0u, 42u, 0u, 999u, k90, k91);
    float g0 = gumbel_exact(tf_bits32(k90, k91, (unsigned)(2*n)));
    float g1 = gumbel_exact(tf_bits32(k90, k91, (unsigned)(2*n + 1)));

    float x0 = __fadd_rn(q0, g0), x1 = __fadd_rn(q1, g1);
    float mmv = fmaxf(x0, x1);
    float ex0 = EXP32(__fsub_rn(x0, mmv));
    float ex1 = EXP32(__fsub_rn(x1, mmv));
    float ssum = __fadd_rn(ex0, ex1);
    float y0 = __fdiv_rn(ex0, ssum), y1 = __fdiv_rn(ex1, ssum);
    int   idx2 = (y1 > y0) ? 1 : 0;
    float ysel = idx2 ? y1 : y0;
    float c    = __fsub_rn(__fadd_rn(1.0f, ysel), ysel);
    sc_s[t][0] = (idx2 == 0) ? c : 0.0f;
    sc_s[t][1] = (idx2 == 1) ? c : 0.0f;

    float m3 = fmaxf(q0, q1);
    float t0 = __fsub_rn(q0, m3), t1 = __fsub_rn(q1, m3);
    float se2 = __fadd_rn(EXP32(t0), EXP32(t1));
    float l21 = __fsub_rn(t1, LOG32(se2));
    if (msk != 0 && (n & (LL-1)) != 0) atomicAdd(&wsF[WSF_CLS], l21);
  }

  gbar(&wsI[WSI_BAR], GRIDN);

  // ================= PHASE 2: gathered GEMM, dynamic tickets, f64 acc
  const int units = PP * 8 * 16 * KS;
  while (true){
    __syncthreads();
    if (t == 0) s_unit = atomicAdd(&wsI[WSI_TKT], 1);
    __syncthreads();
    int u = s_unit;
    if (u >= units) break;
    int p  = u % PP;       u /= PP;
    int rt = u & 7;        u >>= 3;
    int ct = u & 15;       u >>= 4;
    int kh = u;            // 0..KS-1
    int cnt0 = wsI[WSI_CNT + p];
    int cnt  = cnt0 < LISTCAP ? cnt0 : LISTCAP;
    int r0 = rt * RT;
    if (r0 >= cnt) continue;
    int c0 = ct * CT;

    if (t < RT){
      int rr = r0 + t;
      rid_s[t] = wsI[WSI_ROWLIST + p*LISTCAP + (rr < cnt ? rr : cnt-1)];
    }
    __syncthreads();

    const int tr = t >> 4, tc = t & 15;
    double acc[4][4];
    #pragma unroll
    for (int i = 0; i < 4; ++i)
      #pragma unroll
      for (int j = 0; j < 4; ++j) acc[i][j] = 0.0;

    const float* Wp = dec_W + (size_t)p * HSZ * MM;
    const int kbeg = kh * (HSZ / KS);
    const int kend = kbeg + (HSZ / KS);

    for (int k0 = kbeg; k0 < kend; k0 += BK){
      #pragma unroll
      for (int i = 0; i < 4; ++i){
        int s = t + i*256;          // 0..1023
        int r = s >> 4, q = s & 15;
        float4 v = *(const float4*)(ctx + (size_t)rid_s[r]*HSZ + k0 + q*4);
        As[q*4+0][r] = v.x; As[q*4+1][r] = v.y; As[q*4+2][r] = v.z; As[q*4+3][r] = v.w;
      }
      #pragma unroll
      for (int i = 0; i < 4; ++i){
        int s = t + i*256;
        int kk = s >> 4, q = s & 15;
        float4 v = *(const float4*)(Wp + (size_t)(k0+kk)*MM + c0 + q*4);
        *(float4*)&Bs[kk][q*4] = v;
      }
      __syncthreads();
      #pragma unroll 4
      for (int kk = 0; kk < BK; ++kk){
        float4 af = *(const float4*)&As[kk][tr*4];
        float4 bf = *(const float4*)&Bs[kk][tc*4];
        double a0=(double)af.x, a1=(double)af.y, a2=(double)af.z, a3=(double)af.w;
        double b0=(double)bf.x, b1=(double)bf.y, b2=(double)bf.z, b3=(double)bf.w;
        acc[0][0]+=a0*b0; acc[0][1]+=a0*b1; acc[0][2]+=a0*b2; acc[0][3]+=a0*b3;
        acc[1][0]+=a1*b0; acc[1][1]+=a1*b1; acc[1][2]+=a1*b2; acc[1][3]+=a1*b3;
        acc[2][0]+=a2*b0; acc[2][1]+=a2*b1; acc[2][2]+=a2*b2; acc[2][3]+=a2*b3;
        acc[3][0]+=a3*b0; acc[3][1]+=a3*b1; acc[3][2]+=a3*b2; acc[3][3]+=a3*b3;
      }
      __syncthreads();
    }

    float* dst = (kh == 0) ? lg0 : lg1;
    #pragma unroll
    for (int i = 0; i < 4; ++i){
      int rr = r0 + tr*4 + i;
      if (rr < cnt){
        int rg = rid_s[tr*4 + i];
        float4 o;
        o.x=(float)acc[i][0]; o.y=(float)acc[i][1]; o.z=(float)acc[i][2]; o.w=(float)acc[i][3];
        *(float4*)(dst + (size_t)rg*MM + c0 + tc*4) = o;
      }
    }
  }

  gbar(&wsI[WSI_BAR], 2*GRIDN);

  // ================= PHASE 3: finalize rows bid*8..+7
  for (int i = 0; i < RPB; ++i){
    __syncthreads();
    const int n = bid*RPB + i;
    const int  pos   = inp_pos[n];
    const int  word  = inp_word[n];
    const int  msk   = inp_mask[n];
    const bool isobf = (pos < PP);
    const bool ispri = (pos < 4);
    const float c0 = sc_s[i][0], c1 = sc_s[i][1];

    if (isobf){
      const int m0 = 4*t;
      float4 ha = *(const float4*)(lg0 + (size_t)n*MM + m0);
      float l0, l1, l2, l3;
      if (KS == 2){
        float4 hb = *(const float4*)(lg1 + (size_t)n*MM + m0);
        l0 = __fadd_rn(ha.x, hb.x); l1 = __fadd_rn(ha.y, hb.y);
        l2 = __fadd_rn(ha.z, hb.z); l3 = __fadd_rn(ha.w, hb.w);
      } else { l0 = ha.x; l1 = ha.y; l2 = ha.z; l3 = ha.w; }
      const float4 bq = *(const float4*)(dec_b + (size_t)pos*MM + m0);
      l0 = __fadd_rn(l0, bq.x); l1 = __fadd_rn(l1, bq.y);
      l2 = __fadd_rn(l2, bq.z); l3 = __fadd_rn(l3, bq.w);

      float lm = fmaxf(fmaxf(l0, l1), fmaxf(l2, l3));
      #pragma unroll
      for (int off = 32; off > 0; off >>= 1) lm = fmaxf(lm, __shfl_xor(lm, off));
      if (lane == 0) sMax[wid] = lm;
      __syncthreads();
      const float xmax = fmaxf(fmaxf(sMax[0], sMax[1]), fmaxf(sMax[2], sMax[3]));

      float e0 = expf(__fsub_rn(l0, xmax));
      float e1 = expf(__fsub_rn(l1, xmax));
      float e2 = expf(__fsub_rn(l2, xmax));
      float e3 = expf(__fsub_rn(l3, xmax));
      double ds = (((double)e0 + (double)e1) + (double)e2) + (double)e3;
      #pragma unroll
      for (int off = 32; off > 0; off >>= 1) ds += __shfl_xor(ds, off);
      if (lane == 0) sSum[wid] = ds;
      __syncthreads();
      const double se = ((sSum[0] + sSum[1]) + sSum[2]) + sSum[3];
      const float lse = logf((float)se);
      const double inv_se = 1.0 / se;

      unsigned kp0, kp1; tf2x32(0u, 42u, 0u, (unsigned)pos, kp0, kp1);
      float best = -3.4e38f; int bi = 0; double es = 0.0;
      float lv[4] = {l0, l1, l2, l3};
      float ev[4] = {e0, e1, e2, e3};
      #pragma unroll
      for (int j = 0; j < 4; ++j){
        int m = m0 + j;
        float sh = __fsub_rn(lv[j], xmax);
        float lp = __fsub_rn(sh, lse);
        es += (double)(-lp) * ((double)ev[j] * inv_se);
        float g = gumbel_fast(tf_bits32(kp0, kp1, (unsigned)(n*MM + m)));
        float sv = __fadd_rn(lp, g);
        if (sv > best){ best = sv; bi = m; }
      }
      #pragma unroll
      for (int off = 32; off > 0; off >>= 1){
        float ov = __shfl_xor(best, off);
        int   oi = __shfl_xor(bi,   off);
        if (ov > best || (ov == best && oi < bi)){ best = ov; bi = oi; }
        es += __shfl_xor(es, off);
      }
      if (lane == 0){ sBv[wid] = best; sBi[wid] = bi; sEnt[wid] = es; }
      __syncthreads();
      if (t == 0){
        float bv = sBv[0]; int b = sBi[0];
        #pragma unroll
        for (int w = 1; w < 4; ++w)
          if (sBv[w] > bv || (sBv[w] == bv && sBi[w] < b)){ bv = sBv[w]; b = sBi[w]; }
        s_si = b;
        atomicAdd(&wsF[WSF_ENT + pos], (float)(((sEnt[0] + sEnt[1]) + sEnt[2]) + sEnt[3]));
      }
      __syncthreads();
    }

    const int idx = isobf ? s_si : 0;
    const int obf_word = isobf ? words[pos*MM + idx] : word;

    float of = __fadd_rn(__fmul_rn((float)word, c0), __fmul_rn((float)obf_word, c1));
    int ow = (int)of;
    if (t == 0){
      out[OFF_WORD + n] = (float)ow;
      bool cpym = (c0 == 1.0f) && (msk != 0);
      out[OFF_CPYM + n] = cpym ? 1.f : 0.f;
      out[OFF_OBFM + n] = (isobf && !cpym) ? 1.f : 0.f;
      out[OFF_PRIM + n] = ispri ? 1.f : 0.f;
    }
    if (t < CLEN)
      out[OFF_CHAR + (size_t)n*CLEN + t] = (float)lut[(size_t)ow*CLEN + t];
    if (t < DD){
      float po = psr_w[(size_t)word*DD + t];
      float pb = isobf ? psr_w[(size_t)obf_word*DD + t] : po;
      out[OFF_PSR + (size_t)n*DD + t] = __fadd_rn(__fmul_rn(po, c0), __fmul_rn(pb, c1));
      float ao = atk_w[(size_t)word*DD + t];
      float ab = isobf ? atk_w[(size_t)obf_word*DD + t] : ao;
      out[OFF_ATK + (size_t)n*DD + t] = __fadd_rn(__fmul_rn(ao, c0), __fmul_rn(ab, c1));
    }
  }

  gbar(&wsI[WSI_BAR], 3*GRIDN);

  // ================= PHASE 4: scalar losses (block 0, thread 0)
  if (bid == 0 && t == 0){
    float ent = 0.f;
    for (int p = 0; p < PP; ++p){
      int c = atomicAdd(&wsI[WSI_CNT + p], 0);
      if (c > 0){
        int denom = c * MM; if (denom < 1) denom = 1;
        float ep = atomicAdd(&wsF[WSF_ENT + p], 0.0f);
        ent = __fadd_rn(ent, __fdiv_rn(ep, (float)denom));
      }
    }
    out[OFF_ELOSS] = -ent;
    int nrc = atomicAdd(&wsI[WSI_NR], 0); if (nrc < 1) nrc = 1;
    float cl = atomicAdd(&wsF[WSF_CLS], 0.0f);
    out[OFF_CLOSS] = -__fdiv_rn(cl, (float)nrc);
  }
}

// =====================  FALLBACK PATH (r4 kernels, proven)  =====================
__global__ __launch_bounds__(256)
void build_idx(const int* __restrict__ inp_pos, int* __restrict__ cntg,
               int* __restrict__ rowlist)
{
  int n = blockIdx.x*256 + threadIdx.x;
  if (n < NTOT){
    int p = inp_pos[n];
    if (p < PP){
      int slot = atomicAdd(&cntg[p], 1);
      if (slot < LISTCAP) rowlist[p*LISTCAP + slot] = n;
    }
  }
}

__global__ __launch_bounds__(256)
void cpy_kernel(const float* __restrict__ ctx, const float* __restrict__ cW1,
                const float* __restrict__ cb1, const float* __restrict__ cW2,
                const float* __restrict__ cb2, const int* __restrict__ inp_pos,
                const int* __restrict__ inp_mask,
                float* __restrict__ scbuf, float* __restrict__ ws)
{
  const int n = blockIdx.x;
  const int t = threadIdx.x;
  __shared__ float  ctxl[HSZ];
  __shared__ double part[256];
  __shared__ float  hsh[64];

  if (t < 128) *(float4*)&ctxl[t*4] = *(const float4*)(ctx + (size_t)n*HSZ + t*4);
  __syncthreads();

  const int o = t & 63, seg = t >> 6;
  {
    double a = 0.0;
    const float* w  = cW1 + (size_t)(seg*128)*64 + o;
    const float* cs = ctxl + seg*128;
    #pragma unroll 8
    for (int kk = 0; kk < 128; ++kk) a += (double)cs[kk] * (double)w[kk*64];
    part[t] = a;
  }
  __syncthreads();
  if (t < 64){
    double s = ((part[t] + part[64+t]) + part[128+t]) + part[192+t];
    float hv = __fadd_rn((float)s, cb1[t]);
    hsh[t] = hv > 0.f ? hv : 0.f;
  }
  __syncthreads();

  if (t < 64){
    double hd = (double)hsh[t];
    double p0 = hd * (double)cW2[2*t + 0];
    double p1 = hd * (double)cW2[2*t + 1];
    #pragma unroll
    for (int off = 32; off > 0; off >>= 1){
      p0 += __shfl_xor(p0, off);
      p1 += __shfl_xor(p1, off);
    }
    if (t == 0){
      const int pos = inp_pos[n];
      const int msk = inp_mask[n];
      const bool ispri = (pos < 4);
      float pc0 = __fadd_rn((float)p0, cb2[0]);
      float pc1 = __fadd_rn((float)p1, cb2[1]);
      float m2  = fmaxf(pc0, pc1);
      float s0  = __fsub_rn(pc0, m2), s1 = __fsub_rn(pc1, m2);
      float se  = __fadd_rn(EXP32(s0), EXP32(s1));
      float lse = LOG32(se);
      float q0  = __fsub_rn(s0, lse), q1 = __fsub_rn(s1, lse);
      if (ispri){ q0 = 0.0f; q1 = 1.0f; }

      unsigned k90, k91; tf2x32(0u, 42u, 0u, 999u, k90, k91);
      float g0 = gumbel_exact(tf_bits32(k90, k91, (unsigned)(2*n)));
      float g1 = gumbel_exact(tf_bits32(k90, k91, (unsigned)(2*n + 1)));

      float x0 = __fadd_rn(q0, g0), x1 = __fadd_rn(q1, g1);
      float mmv = fmaxf(x0, x1);
      float ex0 = EXP32(__fsub_rn(x0, mmv));
      float ex1 = EXP32(__fsub_rn(x1, mmv));
      float ssum = __fadd_rn(ex0, ex1);
      float y0 = __fdiv_rn(ex0, ssum), y1 = __fdiv_rn(ex1, ssum);
      int   idx2 = (y1 > y0) ? 1 : 0;
      float ysel = idx2 ? y1 : y0;
      float c    = __fsub_rn(__fadd_rn(1.0f, ysel), ysel);
      scbuf[2*n + 0] = (idx2 == 0) ? c : 0.0f;
      scbuf[2*n + 1] = (idx2 == 1) ? c : 0.0f;

      float m3 = fmaxf(q0, q1);
      float t0 = __fsub_rn(q0, m3), t1 = __fsub_rn(q1, m3);
      float se2 = __fadd_rn(EXP32(t0), EXP32(t1));
      float l21 = __fsub_rn(t1, LOG32(se2));
      if (msk != 0 && (n & (LL-1)) != 0) atomicAdd(ws + 12, l21);
    }
  }
}

__global__ __launch_bounds__(256)
void gemm_kernel(const float* __restrict__ ctx, const float* __restrict__ dec_W,
                 const int* __restrict__ cntg, const int* __restrict__ rowlist,
                 float* __restrict__ logits)
{
  const int p  = blockIdx.z;
  const int c0 = blockIdx.x * CT;
  const int r0 = blockIdx.y * RT;
  const int cnt0 = cntg[p];
  const int cnt  = cnt0 < LISTCAP ? cnt0 : LISTCAP;
  if (r0 >= cnt) return;
  const int t = threadIdx.x;

  __shared__ float As[BK][RT+4];
  __shared__ float Bs[BK][CT+4];
  __shared__ int   rid_s[RT];

  if (t < RT){
    int rr = r0 + t;
    rid_s[t] = rowlist[p*LISTCAP + (rr < cnt ? rr : cnt-1)];
  }
  __syncthreads();

  const int tr = t >> 4, tc = t & 15;
  double acc[4][4];
  #pragma unroll
  for (int i = 0; i < 4; ++i)
    #pragma unroll
    for (int j = 0; j < 4; ++j) acc[i][j] = 0.0;

  const float* Wp = dec_W + (size_t)p * HSZ * MM;
  for (int k0 = 0; k0 < HSZ; k0 += BK){
    #pragma unroll
    for (int i = 0; i < 4; ++i){
      int s = t + i*256;
      int r = s >> 4, q = s & 15;
      float4 v = *(const float4*)(ctx + (size_t)rid_s[r]*HSZ + k0 + q*4);
      As[q*4+0][r] = v.x; As[q*4+1][r] = v.y; As[q*4+2][r] = v.z; As[q*4+3][r] = v.w;
    }
    #pragma unroll
    for (int i = 0; i < 4; ++i){
      int s = t + i*256;
      int kk = s >> 4, q = s & 15;
      float4 v = *(const float4*)(Wp + (size_t)(k0+kk)*MM + c0 + q*4);
      *(float4*)&Bs[kk][q*4] = v;
    }
    __syncthreads();
    #pragma unroll 4
    for (int kk = 0; kk < BK; ++kk){
      float4 af = *(const float4*)&As[kk][tr*4];
      float4 bf = *(const float4*)&Bs[kk][tc*4];
      double a0=(double)af.x, a1=(double)af.y, a2=(double)af.z, a3=(double)af.w;
      double b0=(double)bf.x, b1=(double)bf.y, b2=(double)bf.z, b3=(double)bf.w;
      acc[0][0]+=a0*b0; acc[0][1]+=a0*b1; acc[0][2]+=a0*b2; acc[0][3]+=a0*b3;
      acc[1][0]+=a1*b0; acc[1][1]+=a1*b1; acc[1][2]+=a1*b2; acc[1][3]+=a1*b3;
      acc[2][0]+=a2*b0; acc[2][1]+=a2*b1; acc[2][2]+=a2*b2; acc[2][3]+=a2*b3;
      acc[3][0]+=a3*b0; acc[3][1]+=a3*b1; acc[3][2]+=a3*b2; acc[3][3]+=a3*b3;
    }
    __syncthreads();
  }

  #pragma unroll
  for (int i = 0; i < 4; ++i){
    int rr = r0 + tr*4 + i;
    if (rr < cnt){
      int rg = rid_s[tr*4 + i];
      float4 o;
      o.x=(float)acc[i][0]; o.y=(float)acc[i][1]; o.z=(float)acc[i][2]; o.w=(float)acc[i][3];
      *(float4*)(logits + (size_t)rg*MM + c0 + tc*4) = o;
    }
  }
}

__global__ __launch_bounds__(256)
void finalize_kernel(const float* __restrict__ dec_b,
                     const float* __restrict__ psr_w, const float* __restrict__ atk_w,
                     const int* __restrict__ inp_word, const int* __restrict__ inp_pos,
                     const int* __restrict__ inp_mask, const int* __restrict__ words,
                     const int* __restrict__ lut, const float* __restrict__ logitsbuf,
                     const float* __restrict__ scbuf,
                     float* __restrict__ out, float* __restrict__ ws)
{
  const int n = blockIdx.x;
  const int t = threadIdx.x;
  const int wid = t >> 6, lane = t & 63;

  __shared__ float  sMax[4];
  __shared__ double sSum[4];
  __shared__ double sEnt[4];
  __shared__ float  sBv[4];
  __shared__ int    sBi[4];
  __shared__ int    si;

  const int  pos   = inp_pos[n];
  const int  word  = inp_word[n];
  const int  msk   = inp_mask[n];
  const bool isobf = (pos < PP);
  const bool ispri = (pos < 4);
  const float c0 = scbuf[2*n + 0];
  const float c1 = scbuf[2*n + 1];

  if (isobf){
    const int m0 = 4*t;
    const float4 lg = *(const float4*)(logitsbuf + (size_t)n*MM + m0);
    const float4 bq = *(const float4*)(dec_b + (size_t)pos*MM + m0);
    float l0 = __fadd_rn(lg.x, bq.x);
    float l1 = __fadd_rn(lg.y, bq.y);
    float l2 = __fadd_rn(lg.z, bq.z);
    float l3 = __fadd_rn(lg.w, bq.w);

    float lm = fmaxf(fmaxf(l0, l1), fmaxf(l2, l3));
    #pragma unroll
    for (int off = 32; off > 0; off >>= 1) lm = fmaxf(lm, __shfl_xor(lm, off));
    if (lane == 0) sMax[wid] = lm;
    __syncthreads();
    const float xmax = fmaxf(fmaxf(sMax[0], sMax[1]), fmaxf(sMax[2], sMax[3]));

    float e0 = EXP32(__fsub_rn(l0, xmax));
    float e1 = EXP32(__fsub_rn(l1, xmax));
    float e2 = EXP32(__fsub_rn(l2, xmax));
    float e3 = EXP32(__fsub_rn(l3, xmax));
    double ds = (((double)e0 + (double)e1) + (double)e2) + (double)e3;
    #pragma unroll
    for (int off = 32; off > 0; off >>= 1) ds += __shfl_xor(ds, off);
    if (lane == 0) sSum[wid] = ds;
    __syncthreads();
    const double se = ((sSum[0] + sSum[1]) + sSum[2]) + sSum[3];
    const float lse = LOG32((float)se);
    const double inv_se = 1.0 / se;

    unsigned kp0, kp1; tf2x32(0u, 42u, 0u, (unsigned)pos, kp0, kp1);
    float best = -3.4e38f; int bi = 0; double es = 0.0;
    float lv[4] = {l0, l1, l2, l3};
    float ev[4] = {e0, e1, e2, e3};
    #pragma unroll
    for (int j = 0; j < 4; ++j){
      int m = m0 + j;
      float sh = __fsub_rn(lv[j], xmax);
      float lp = __fsub_rn(sh, lse);
      es += (double)(-lp) * ((double)ev[j] * inv_se);
      float g = gumbel_exact(tf_bits32(kp0, kp1, (unsigned)(n*MM + m)));
      float sv = __fadd_rn(lp, g);
      if (sv > best){ best = sv; bi = m; }
    }
    #pragma unroll
    for (int off = 32; off > 0; off >>= 1){
      float ov = __shfl_xor(best, off);
      int   oi = __shfl_xor(bi,   off);
      if (ov > best || (ov == best && oi < bi)){ best = ov; bi = oi; }
      es += __shfl_xor(es, off);
    }
    if (lane == 0){ sBv[wid] = best; sBi[wid] = bi; sEnt[wid] = es; }
    __syncthreads();
    if (t == 0){
      float bv = sBv[0]; int b = sBi[0];
      #pragma unroll
      for (int w = 1; w < 4; ++w)
        if (sBv[w] > bv || (sBv[w] == bv && sBi[w] < b)){ bv = sBv[w]; b = sBi[w]; }
      si = b;
      atomicAdd(ws + pos, (float)(((sEnt[0] + sEnt[1]) + sEnt[2]) + sEnt[3]));
    }
    __syncthreads();
  }

  const int   idx = isobf ? si : 0;
  const int   obf_word = isobf ? words[pos*MM + idx] : word;

  float of = __fadd_rn(__fmul_rn((float)word, c0), __fmul_rn((float)obf_word, c1));
  int ow = (int)of;
  if (t == 0){
    out[OFF_WORD + n] = (float)ow;
    bool cpym = (c0 == 1.0f) && (msk != 0);
    out[OFF_CPYM + n] = cpym ? 1.f : 0.f;
    out[OFF_OBFM + n] = (isobf && !cpym) ? 1.f : 0.f;
    out[OFF_PRIM + n] = ispri ? 1.f : 0.f;
  }
  if (t < CLEN)
    out[OFF_CHAR + (size_t)n*CLEN + t] = (float)lut[(size_t)ow*CLEN + t];
  if (t < DD){
    float po = psr_w[(size_t)word*DD + t];
    float pb = isobf ? psr_w[(size_t)obf_word*DD + t] : po;
    out[OFF_PSR + (size_t)n*DD + t] = __fadd_rn(__fmul_rn(po, c0), __fmul_rn(pb, c1));
    float ao = atk_w[(size_t)word*DD + t];
    float ab = isobf ? atk_w[(size_t)obf_word*DD + t] : ao;
    out[OFF_ATK + (size_t)n*DD + t] = __fadd_rn(__fmul_rn(ao, c0), __fmul_rn(ab, c1));
  }
}

__global__ __launch_bounds__(256)
void fin_kernel(const int* __restrict__ inp_pos, const int* __restrict__ inp_mask,
                const float* __restrict__ ws, float* __restrict__ out)
{
  __shared__ int cnt[PP];
  __shared__ int nr;
  int t = threadIdx.x;
  if (t < PP) cnt[t] = 0;
  if (t == 0) nr = 0;
  __syncthreads();
  int ln = 0;
  for (int n = t; n < NTOT; n += 256){
    int p = inp_pos[n];
    if (p < PP) atomicAdd(&cnt[p], 1);
    if (inp_mask[n] != 0 && (n & (LL-1)) != 0) ln++;
  }
  atomicAdd(&nr, ln);
  __syncthreads();
  if (t == 0){
    float ent = 0.f;
    for (int p = 0; p < PP; ++p){
      int c = cnt[p];
      if (c > 0){
        int denom = c * MM; if (denom < 1) denom = 1;
        ent = __fadd_rn(ent, __fdiv_rn(ws[p], (float)denom));
      }
    }
    out[OFF_ELOSS] = -ent;
    int nrc = nr; if (nrc < 1) nrc = 1;
    out[OFF_CLOSS] = -__fdiv_rn(ws[12], (float)nrc);
  }
}

extern "C" void kernel_launch(void* const* d_in, const int* in_sizes, int n_in,
                              void* d_out, int out_size, void* d_ws, size_t ws_size,
                              hipStream_t stream)
{
  const float* ctx      = (const float*)d_in[0];
  const float* dec_W    = (const float*)d_in[1];
  const float* dec_b    = (const float*)d_in[2];
  const float* psr_w    = (const float*)d_in[3];
  const float* atk_w    = (const float*)d_in[4];
  const float* cW1      = (const float*)d_in[5];
  const float* cb1      = (const float*)d_in[6];
  const float* cW2      = (const float*)d_in[7];
  const float* cb2      = (const float*)d_in[8];
  const int*   inp_word = (const int*)d_in[9];
  const int*   inp_pos  = (const int*)d_in[10];
  const int*   inp_mask = (const int*)d_in[11];
  const int*   words    = (const int*)d_in[12];
  const int*   lut      = (const int*)d_in[13];
  float* out = (float*)d_out;
  float* ws  = (float*)d_ws;

  const size_t need1 = ((size_t)WS_LOGITS_OFF + 1ull*NTOT*MM) * 4;
  const size_t need2 = ((size_t)WS_LOGITS_OFF + 2ull*NTOT*MM) * 4;

  hipMemsetAsync(ws, 0, 512, stream);

  if (ws_size >= need1){
    int KS = (ws_size >= need2) ? 2 : 1;
    int*   wsI = (int*)ws;
    float* lg0 = ws + WS_LOGITS_OFF;
    float* lg1 = (KS == 2) ? (lg0 + (size_t)NTOT*MM) : lg0;
    fused_kernel<<<GRIDN, 256, 0, stream>>>(ctx, dec_W, dec_b, psr_w, atk_w,
                                            cW1, cb1, cW2, cb2,
                                            inp_word, inp_pos, inp_mask, words, lut,
                                            out, wsI, ws, lg0, lg1, KS);
  } else {
    // fallback: proven r4 multi-kernel path
    int*   cntg      = (int*)ws + 16;
    int*   rowlist   = (int*)ws + WSI_ROWLIST;
    float* scbuf     = ws + WS_SC_OFF;
    float* logitsbuf = ws + WS_LOGITS_OFF;
    build_idx<<<NTOT/256, 256, 0, stream>>>(inp_pos, cntg, rowlist);
    cpy_kernel<<<NTOT, 256, 0, stream>>>(ctx, cW1, cb1, cW2, cb2,
                                         inp_pos, inp_mask, scbuf, ws);
    gemm_kernel<<<dim3(MM/CT, LISTCAP/RT, PP), 256, 0, stream>>>(ctx, dec_W, cntg, rowlist, logitsbuf);
    finalize_kernel<<<NTOT, 256, 0, stream>>>(dec_b, psr_w, atk_w,
                                              inp_word, inp_pos, inp_mask, words, lut,
                                              logitsbuf, scbuf, out, ws);
    fin_kernel<<<1, 256, 0, stream>>>(inp_pos, inp_mask, ws, out);
  }
}

// Round 6
// 330.852 us; speedup vs baseline: 1.8073x; 1.8073x over previous
//
#include <hip/hip_runtime.h>
#include <math.h>

// ---- problem constants ----
#define BB 32
#define LL 128
#define HSZ 512
#define PP 12
#define MM 1024
#define VV 50000
#define DD 128
#define CLEN 16
#define NTOT 4096           // B*L
#define LISTCAP 512

// GEMM tiling: 64x64 tiles, BK=64, 4x4 acc/thread (r3 shape, r4 conflict-free layout)
#define RT 64
#define CT 64
#define BK 64
// cpy tiling
#define CPB 16              // rows per cpy block

// output offsets (floats)
#define OFF_WORD  0
#define OFF_CHAR  4096
#define OFF_PSR   69632
#define OFF_ATK   593920
#define OFF_OBFM  1118208
#define OFF_CPYM  1122304
#define OFF_PRIM  1126400
#define OFF_CLOSS 1130496
#define OFF_ELOSS 1130497

// ws layout: floats [0..11]=ent partials [12]=closs ; ints [16..27]=cnt ;
// ints [64..6207]=rowlist ; floats [6656..14847]=scbuf ; floats [16384..]=logits
#define WS_SC_OFF     6656
#define WS_LOGITS_OFF 16384

// ---- CR-f32 transcendentals via double libm (bit-critical gate path) ----
__device__ __forceinline__ float EXP32(float x){ return (float)exp((double)x); }
__device__ __forceinline__ float LOG32(float x){ return (float)log((double)x); }

// ---- JAX threefry2x32 (20 rounds) — verified vs known-answer vector ----
__device__ __forceinline__ unsigned rotl32(unsigned x, int r){ return (x<<r)|(x>>(32-r)); }
__device__ __forceinline__ void tf2x32(unsigned k0, unsigned k1, unsigned x0, unsigned x1,
                                       unsigned &o0, unsigned &o1){
  unsigned ks2 = k0 ^ k1 ^ 0x1BD11BDAu;
  x0 += k0; x1 += k1;
  x0+=x1; x1=rotl32(x1,13); x1^=x0;
  x0+=x1; x1=rotl32(x1,15); x1^=x0;
  x0+=x1; x1=rotl32(x1,26); x1^=x0;
  x0+=x1; x1=rotl32(x1, 6); x1^=x0;
  x0+=k1; x1+=ks2+1u;
  x0+=x1; x1=rotl32(x1,17); x1^=x0;
  x0+=x1; x1=rotl32(x1,29); x1^=x0;
  x0+=x1; x1=rotl32(x1,16); x1^=x0;
  x0+=x1; x1=rotl32(x1,24); x1^=x0;
  x0+=ks2; x1+=k0+2u;
  x0+=x1; x1=rotl32(x1,13); x1^=x0;
  x0+=x1; x1=rotl32(x1,15); x1^=x0;
  x0+=x1; x1=rotl32(x1,26); x1^=x0;
  x0+=x1; x1=rotl32(x1, 6); x1^=x0;
  x0+=k0; x1+=k1+3u;
  x0+=x1; x1=rotl32(x1,17); x1^=x0;
  x0+=x1; x1=rotl32(x1,29); x1^=x0;
  x0+=x1; x1=rotl32(x1,16); x1^=x0;
  x0+=x1; x1=rotl32(x1,24); x1^=x0;
  x0+=k1; x1+=ks2+4u;
  x0+=x1; x1=rotl32(x1,13); x1^=x0;
  x0+=x1; x1=rotl32(x1,15); x1^=x0;
  x0+=x1; x1=rotl32(x1,26); x1^=x0;
  x0+=x1; x1=rotl32(x1, 6); x1^=x0;
  x0+=ks2; x1+=k0+5u;
  o0=x0; o1=x1;
}

// jax_threefry_partitionable=True random_bits: count (0,e), output o0^o1
__device__ __forceinline__ unsigned tf_bits32(unsigned k0, unsigned k1, unsigned e){
  unsigned o0, o1; tf2x32(k0, k1, 0u, e, o0, o1); return o0 ^ o1;
}

__device__ __forceinline__ float bits_to_unif(unsigned bits){
  const float lo = 1e-6f;
  const float hi = (float)(1.0 - 1e-6);
  const float span = hi - lo;
  unsigned fb = (bits >> 9) | 0x3f800000u;
  float f = __fsub_rn(__uint_as_float(fb), 1.0f);
  float r = __fadd_rn(__fmul_rn(f, span), lo);
  return fmaxf(lo, r);
}

// exact (CR) gumbel — cpy gate only (bit-critical: decides c in {1,1-2^-24})
__device__ __forceinline__ float gumbel_exact(unsigned bits){
  float u = bits_to_unif(bits);
  float v = -LOG32(u);
  return -LOG32(v);
}
// fast (ocml f32) gumbel — finalize argmax path (proven r5)
__device__ __forceinline__ float gumbel_fast(unsigned bits){
  float u = bits_to_unif(bits);
  float v = -logf(u);
  return -logf(v);
}

// ---- the copy-gate chain (CR double-libm path, bit-identical r2-r5) ----
__device__ __forceinline__ void gate_chain(int n, int pos, int msk,
                                           float p0f, float p1f,
                                           const float* __restrict__ cb2,
                                           float* __restrict__ sc0,
                                           float* __restrict__ sc1,
                                           float* __restrict__ closs)
{
  const bool ispri = (pos < 4);
  float pc0 = __fadd_rn(p0f, cb2[0]);
  float pc1 = __fadd_rn(p1f, cb2[1]);
  float m2  = fmaxf(pc0, pc1);
  float s0  = __fsub_rn(pc0, m2), s1 = __fsub_rn(pc1, m2);
  float se  = __fadd_rn(EXP32(s0), EXP32(s1));
  float lse = LOG32(se);
  float q0  = __fsub_rn(s0, lse), q1 = __fsub_rn(s1, lse);
  if (ispri){ q0 = 0.0f; q1 = 1.0f; }

  unsigned k90, k91; tf2x32(0u, 42u, 0u, 999u, k90, k91);
  float g0 = gumbel_exact(tf_bits32(k90, k91, (unsigned)(2*n)));
  float g1 = gumbel_exact(tf_bits32(k90, k91, (unsigned)(2*n + 1)));

  float x0 = __fadd_rn(q0, g0), x1 = __fadd_rn(q1, g1);
  float mmv = fmaxf(x0, x1);
  float ex0 = EXP32(__fsub_rn(x0, mmv));
  float ex1 = EXP32(__fsub_rn(x1, mmv));
  float ssum = __fadd_rn(ex0, ex1);
  float y0 = __fdiv_rn(ex0, ssum), y1 = __fdiv_rn(ex1, ssum);
  int   idx2 = (y1 > y0) ? 1 : 0;
  float ysel = idx2 ? y1 : y0;
  float c    = __fsub_rn(__fadd_rn(1.0f, ysel), ysel);
  *sc0 = (idx2 == 0) ? c : 0.0f;
  *sc1 = (idx2 == 1) ? c : 0.0f;

  float m3 = fmaxf(q0, q1);
  float t0 = __fsub_rn(q0, m3), t1 = __fsub_rn(q1, m3);
  float se2 = __fadd_rn(EXP32(t0), EXP32(t1));
  float l21 = __fsub_rn(t1, LOG32(se2));
  if (msk != 0 && (n & (LL-1)) != 0) atomicAdd(closs, l21);
}

// ---------- Kernel A: bucket build + tiled cpy MLP/gate (16 rows/block) ----------
__global__ __launch_bounds__(256)
void cpy_build_kernel(const float* __restrict__ ctx, const float* __restrict__ cW1,
                      const float* __restrict__ cb1, const float* __restrict__ cW2,
                      const float* __restrict__ cb2, const int* __restrict__ inp_pos,
                      const int* __restrict__ inp_mask, int* __restrict__ cntg,
                      int* __restrict__ rowlist, float* __restrict__ scbuf,
                      float* __restrict__ ws)
{
  const int n0 = blockIdx.x * CPB;
  const int t = threadIdx.x;

  if (t < CPB){
    int n = n0 + t;
    int p = inp_pos[n];
    if (p < PP){
      int slot = atomicAdd(&cntg[p], 1);
      if (slot < LISTCAP) rowlist[p*LISTCAP + slot] = n;
    }
  }

  __shared__ float W1s[64][68];     // [k][o], padded
  __shared__ float Cs[CPB][68];     // [row][k], padded

  const int r  = t >> 4;            // 0..15  (row)
  const int og = (t & 15) * 4;      // output group of 4
  double acc[4] = {0.0, 0.0, 0.0, 0.0};

  for (int k0 = 0; k0 < HSZ; k0 += 64){
    #pragma unroll
    for (int i = 0; i < 4; ++i){    // W1 chunk 64k x 64o
      int s = t + i*256;
      int kk = s >> 4, q = s & 15;
      float4 v = *(const float4*)(cW1 + (size_t)(k0+kk)*64 + q*4);
      *(float4*)&W1s[kk][q*4] = v;
    }
    {                               // ctx chunk 16 rows x 64 k
      int rr = t >> 4, q = t & 15;
      float4 v = *(const float4*)(ctx + (size_t)(n0+rr)*HSZ + k0 + q*4);
      *(float4*)&Cs[rr][q*4] = v;
    }
    __syncthreads();
    #pragma unroll 4
    for (int kk = 0; kk < 64; ++kk){
      double c = (double)Cs[r][kk];
      acc[0] += c * (double)W1s[kk][og+0];
      acc[1] += c * (double)W1s[kk][og+1];
      acc[2] += c * (double)W1s[kk][og+2];
      acc[3] += c * (double)W1s[kk][og+3];
    }
    __syncthreads();
  }

  // bias + relu + W2 partials, reduce across the 16 lanes of the row
  double p0 = 0.0, p1 = 0.0;
  #pragma unroll
  for (int j = 0; j < 4; ++j){
    float hv = __fadd_rn((float)acc[j], cb1[og+j]);
    hv = hv > 0.f ? hv : 0.f;
    double hd = (double)hv;
    p0 += hd * (double)cW2[2*(og+j)+0];
    p1 += hd * (double)cW2[2*(og+j)+1];
  }
  #pragma unroll
  for (int off = 1; off < 16; off <<= 1){
    p0 += __shfl_xor(p0, off);
    p1 += __shfl_xor(p1, off);
  }

  if ((t & 15) == 0){
    const int n = n0 + r;
    float c0v, c1v;
    gate_chain(n, inp_pos[n], inp_mask[n], (float)p0, (float)p1, cb2,
               &c0v, &c1v, ws + 12);
    scbuf[2*n + 0] = c0v;
    scbuf[2*n + 1] = c1v;
  }
}

// ---------- Kernel B: gathered GEMM 64x64, f64 acc, strict k order ----------
__global__ __launch_bounds__(256)
void gemm_kernel(const float* __restrict__ ctx, const float* __restrict__ dec_W,
                 const int* __restrict__ cntg, const int* __restrict__ rowlist,
                 float* __restrict__ logits)
{
  const int p  = blockIdx.z;
  const int c0 = blockIdx.x * CT;
  const int r0 = blockIdx.y * RT;
  const int cnt0 = cntg[p];
  const int cnt  = cnt0 < LISTCAP ? cnt0 : LISTCAP;
  if (r0 >= cnt) return;
  const int t = threadIdx.x;

  __shared__ float As[RT][BK+4];    // [row][k] — r4-proven conflict-free layout
  __shared__ float Bs[BK][CT+4];    // [k][col]
  __shared__ int   rid_s[RT];

  if (t < RT){
    int rr = r0 + t;
    rid_s[t] = rowlist[p*LISTCAP + (rr < cnt ? rr : cnt-1)];
  }
  __syncthreads();

  const int tr = t >> 4, tc = t & 15;
  double acc[4][4];
  #pragma unroll
  for (int i = 0; i < 4; ++i)
    #pragma unroll
    for (int j = 0; j < 4; ++j) acc[i][j] = 0.0;

  const float* Wp = dec_W + (size_t)p * HSZ * MM;

  for (int k0 = 0; k0 < HSZ; k0 += BK){
    #pragma unroll
    for (int i = 0; i < 4; ++i){    // A: 64 rows x 16 float4 along k
      int s = t + i*256;
      int rr = s >> 4, q = s & 15;
      float4 v = *(const float4*)(ctx + (size_t)rid_s[rr]*HSZ + k0 + q*4);
      *(float4*)&As[rr][q*4] = v;
    }
    #pragma unroll
    for (int i = 0; i < 4; ++i){    // B: 64 k x 64 c
      int s = t + i*256;
      int kk = s >> 4, q = s & 15;
      float4 v = *(const float4*)(Wp + (size_t)(k0+kk)*MM + c0 + q*4);
      *(float4*)&Bs[kk][q*4] = v;
    }
    __syncthreads();
    #pragma unroll 4
    for (int kk = 0; kk < BK; ++kk){
      float4 bf = *(const float4*)&Bs[kk][tc*4];
      double b0=(double)bf.x, b1=(double)bf.y, b2=(double)bf.z, b3=(double)bf.w;
      double a0 = (double)As[tr*4+0][kk];
      double a1 = (double)As[tr*4+1][kk];
      double a2 = (double)As[tr*4+2][kk];
      double a3 = (double)As[tr*4+3][kk];
      acc[0][0]+=a0*b0; acc[0][1]+=a0*b1; acc[0][2]+=a0*b2; acc[0][3]+=a0*b3;
      acc[1][0]+=a1*b0; acc[1][1]+=a1*b1; acc[1][2]+=a1*b2; acc[1][3]+=a1*b3;
      acc[2][0]+=a2*b0; acc[2][1]+=a2*b1; acc[2][2]+=a2*b2; acc[2][3]+=a2*b3;
      acc[3][0]+=a3*b0; acc[3][1]+=a3*b1; acc[3][2]+=a3*b2; acc[3][3]+=a3*b3;
    }
    __syncthreads();
  }

  #pragma unroll
  for (int i = 0; i < 4; ++i){
    int rr = r0 + tr*4 + i;
    if (rr < cnt){
      int rg = rid_s[tr*4 + i];
      float4 o;
      o.x=(float)acc[i][0]; o.y=(float)acc[i][1]; o.z=(float)acc[i][2]; o.w=(float)acc[i][3];
      *(float4*)(logits + (size_t)rg*MM + c0 + tc*4) = o;
    }
  }
}

// ---------- Kernel C: finalize, ONE WAVE PER ROW (no __syncthreads) ----------
__global__ __launch_bounds__(256)
void finalize_kernel(const float* __restrict__ dec_b,
                     const float* __restrict__ psr_w, const float* __restrict__ atk_w,
                     const int* __restrict__ inp_word, const int* __restrict__ inp_pos,
                     const int* __restrict__ inp_mask, const int* __restrict__ words,
                     const int* __restrict__ lut, const float* __restrict__ logitsbuf,
                     const float* __restrict__ scbuf,
                     float* __restrict__ out, float* __restrict__ ws)
{
  const int wid = threadIdx.x >> 6, lane = threadIdx.x & 63;
  const int n = blockIdx.x * 4 + wid;

  const int  pos   = inp_pos[n];
  const int  word  = inp_word[n];
  const int  msk   = inp_mask[n];
  const bool isobf = (pos < PP);
  const bool ispri = (pos < 4);
  const float c0 = scbuf[2*n + 0];
  const float c1 = scbuf[2*n + 1];

  int bi = 0;
  if (isobf){
    // load 16 logits per lane (coalesced float4 per iter), add bias
    float l[16];
    float lm = -3.4e38f;
    #pragma unroll
    for (int it = 0; it < 4; ++it){
      int m = it*256 + lane*4;
      float4 lg = *(const float4*)(logitsbuf + (size_t)n*MM + m);
      float4 bq = *(const float4*)(dec_b + (size_t)pos*MM + m);
      l[it*4+0] = __fadd_rn(lg.x, bq.x);
      l[it*4+1] = __fadd_rn(lg.y, bq.y);
      l[it*4+2] = __fadd_rn(lg.z, bq.z);
      l[it*4+3] = __fadd_rn(lg.w, bq.w);
      lm = fmaxf(lm, fmaxf(fmaxf(l[it*4+0], l[it*4+1]), fmaxf(l[it*4+2], l[it*4+3])));
    }
    #pragma unroll
    for (int off = 32; off > 0; off >>= 1) lm = fmaxf(lm, __shfl_xor(lm, off));
    const float xmax = lm;

    float e[16];
    double ds = 0.0;
    #pragma unroll
    for (int j = 0; j < 16; ++j){
      e[j] = expf(__fsub_rn(l[j], xmax));
      ds += (double)e[j];
    }
    #pragma unroll
    for (int off = 32; off > 0; off >>= 1) ds += __shfl_xor(ds, off);
    const double se = ds;
    const float lse = logf((float)se);
    const double inv_se = 1.0 / se;

    unsigned kp0, kp1; tf2x32(0u, 42u, 0u, (unsigned)pos, kp0, kp1);
    float best = -3.4e38f; double es = 0.0;
    #pragma unroll
    for (int it = 0; it < 4; ++it){
      #pragma unroll
      for (int j = 0; j < 4; ++j){
        int m = it*256 + lane*4 + j;
        float sh = __fsub_rn(l[it*4+j], xmax);
        float lp = __fsub_rn(sh, lse);
        es += (double)(-lp) * ((double)e[it*4+j] * inv_se);
        float g = gumbel_fast(tf_bits32(kp0, kp1, (unsigned)(n*MM + m)));
        float sv = __fadd_rn(lp, g);
        if (sv > best){ best = sv; bi = m; }
      }
    }
    #pragma unroll
    for (int off = 32; off > 0; off >>= 1){
      float ov = __shfl_xor(best, off);
      int   oi = __shfl_xor(bi,   off);
      if (ov > best || (ov == best && oi < bi)){ best = ov; bi = oi; }
      es += __shfl_xor(es, off);
    }
    if (lane == 0) atomicAdd(ws + pos, (float)es);
  }

  // ---------- epilogue (per wave = per row) ----------
  const int obf_word = isobf ? words[pos*MM + bi] : word;
  float of = __fadd_rn(__fmul_rn((float)word, c0), __fmul_rn((float)obf_word, c1));
  int ow = (int)of;
  if (lane == 0){
    out[OFF_WORD + n] = (float)ow;
    bool cpym = (c0 == 1.0f) && (msk != 0);
    out[OFF_CPYM + n] = cpym ? 1.f : 0.f;
    out[OFF_OBFM + n] = (isobf && !cpym) ? 1.f : 0.f;
    out[OFF_PRIM + n] = ispri ? 1.f : 0.f;
  }
  if (lane < CLEN)
    out[OFF_CHAR + (size_t)n*CLEN + lane] = (float)lut[(size_t)ow*CLEN + lane];
  #pragma unroll
  for (int rep = 0; rep < 2; ++rep){
    int j = lane + rep*64;
    float po = psr_w[(size_t)word*DD + j];
    float pb = isobf ? psr_w[(size_t)obf_word*DD + j] : po;
    out[OFF_PSR + (size_t)n*DD + j] = __fadd_rn(__fmul_rn(po, c0), __fmul_rn(pb, c1));
    float ao = atk_w[(size_t)word*DD + j];
    float ab = isobf ? atk_w[(size_t)obf_word*DD + j] : ao;
    out[OFF_ATK + (size_t)n*DD + j] = __fadd_rn(__fmul_rn(ao, c0), __fmul_rn(ab, c1));
  }
}

// ---------- losses ----------
__global__ __launch_bounds__(256)
void fin_kernel(const int* __restrict__ inp_pos, const int* __restrict__ inp_mask,
                const float* __restrict__ ws, float* __restrict__ out)
{
  __shared__ int cnt[PP];
  __shared__ int nr;
  int t = threadIdx.x;
  if (t < PP) cnt[t] = 0;
  if (t == 0) nr = 0;
  __syncthreads();
  int ln = 0;
  for (int n = t; n < NTOT; n += 256){
    int p = inp_pos[n];
    if (p < PP) atomicAdd(&cnt[p], 1);
    if (inp_mask[n] != 0 && (n & (LL-1)) != 0) ln++;
  }
  atomicAdd(&nr, ln);
  __syncthreads();
  if (t == 0){
    float ent = 0.f;
    for (int p = 0; p < PP; ++p){
      int c = cnt[p];
      if (c > 0){
        int denom = c * MM; if (denom < 1) denom = 1;
        ent = __fadd_rn(ent, __fdiv_rn(ws[p], (float)denom));
      }
    }
    out[OFF_ELOSS] = -ent;
    int nrc = nr; if (nrc < 1) nrc = 1;
    out[OFF_CLOSS] = -__fdiv_rn(ws[12], (float)nrc);
  }
}

// ---------- monolithic fallback (r2, proven) for tiny ws ----------
__global__ __launch_bounds__(256)
void row_kernel_mono(const float* __restrict__ ctx, const float* __restrict__ dec_W,
                const float* __restrict__ dec_b, const float* __restrict__ psr_w,
                const float* __restrict__ atk_w, const float* __restrict__ cW1,
                const float* __restrict__ cb1, const float* __restrict__ cW2,
                const float* __restrict__ cb2, const int* __restrict__ inp_word,
                const int* __restrict__ inp_pos, const int* __restrict__ inp_mask,
                const int* __restrict__ words, const int* __restrict__ lut,
                float* __restrict__ out, float* __restrict__ ws)
{
  const int n = blockIdx.x;
  const int t = threadIdx.x;

  __shared__ float  ctx_s[HSZ];
  __shared__ float  logit_s[MM];
  __shared__ float  h_s[64];
  __shared__ double redd[256];
  __shared__ float  redf[256];
  __shared__ int    redi[256];
  __shared__ float  sc[2];
  __shared__ int    si[1];

  for (int k = t; k < HSZ; k += 256) ctx_s[k] = ctx[(size_t)n*HSZ + k];
  __syncthreads();

  const int  pos   = inp_pos[n];
  const int  word  = inp_word[n];
  const int  msk   = inp_mask[n];
  const bool isobf = (pos < PP);
  const bool ispri = (pos < 4);

  if (t < 64){
    double acc = 0.0;
    for (int k = 0; k < HSZ; ++k) acc += (double)ctx_s[k] * (double)cW1[k*64 + t];
    float hv = __fadd_rn((float)acc, cb1[t]);
    h_s[t] = hv > 0.f ? hv : 0.f;
  }
  __syncthreads();

  if (t == 0){
    double a0 = 0.0, a1 = 0.0;
    for (int k = 0; k < 64; ++k){
      double hv = (double)h_s[k];
      a0 += hv * (double)cW2[k*2 + 0];
      a1 += hv * (double)cW2[k*2 + 1];
    }
    float c0v, c1v;
    gate_chain(n, pos, msk, (float)a0, (float)a1, cb2, &c0v, &c1v, ws + 12);
    sc[0] = c0v; sc[1] = c1v;
  }

  if (isobf){
    const float4* W4 = (const float4*)(dec_W + (size_t)pos * HSZ * MM);
    double a0=0.0, a1=0.0, a2=0.0, a3=0.0;
    for (int k = 0; k < HSZ; ++k){
      double c = (double)ctx_s[k];
      float4 w = W4[(size_t)k*256 + t];
      a0 += c*(double)w.x; a1 += c*(double)w.y; a2 += c*(double)w.z; a3 += c*(double)w.w;
    }
    const float* bp = dec_b + (size_t)pos * MM;
    const int m0 = 4*t;
    logit_s[m0+0] = __fadd_rn((float)a0, bp[m0+0]);
    logit_s[m0+1] = __fadd_rn((float)a1, bp[m0+1]);
    logit_s[m0+2] = __fadd_rn((float)a2, bp[m0+2]);
    logit_s[m0+3] = __fadd_rn((float)a3, bp[m0+3]);
    __syncthreads();

    float lm = logit_s[m0];
    lm = fmaxf(lm, logit_s[m0+1]); lm = fmaxf(lm, logit_s[m0+2]); lm = fmaxf(lm, logit_s[m0+3]);
    redf[t] = lm; __syncthreads();
    for (int s = 128; s > 0; s >>= 1){ if (t < s) redf[t] = fmaxf(redf[t], redf[t+s]); __syncthreads(); }
    const float xmax = redf[0];
    __syncthreads();

    double dsm = 0.0;
    for (int j = 0; j < 4; ++j)
      dsm += (double)EXP32(__fsub_rn(logit_s[m0+j], xmax));
    redd[t] = dsm; __syncthreads();
    for (int s = 128; s > 0; s >>= 1){ if (t < s) redd[t] += redd[t+s]; __syncthreads(); }
    const float lse = LOG32((float)redd[0]);
    __syncthreads();

    unsigned kp0, kp1; tf2x32(0u, 42u, 0u, (unsigned)pos, kp0, kp1);
    float best = -3.4e38f; int bi = 0; double es = 0.0;
    for (int j = 0; j < 4; ++j){
      int m = m0 + j;
      float sh = __fsub_rn(logit_s[m], xmax);
      float lp = __fsub_rn(sh, lse);
      float ex = EXP32(lp);
      es += (double)__fmul_rn(-lp, ex);
      float g = gumbel_exact(tf_bits32(kp0, kp1, (unsigned)(n*MM + m)));
      float sv = __fadd_rn(lp, g);
      if (sv > best){ best = sv; bi = m; }
    }
    redf[t] = best; redi[t] = bi; redd[t] = es; __syncthreads();
    for (int s = 128; s > 0; s >>= 1){
      if (t < s){
        float v2 = redf[t+s]; int i2 = redi[t+s];
        if (v2 > redf[t] || (v2 == redf[t] && i2 < redi[t])){ redf[t] = v2; redi[t] = i2; }
        redd[t] += redd[t+s];
      }
      __syncthreads();
    }
    if (t == 0){ si[0] = redi[0]; atomicAdd(ws + pos, (float)redd[0]); }
    __syncthreads();
  } else {
    __syncthreads();
  }

  const int   idx = isobf ? si[0] : 0;
  const float c0 = sc[0], c1 = sc[1];
  const int   obf_word = isobf ? words[pos*MM + idx] : word;

  if (t == 0){
    float of = __fadd_rn(__fmul_rn((float)word, c0), __fmul_rn((float)obf_word, c1));
    int ow = (int)of;
    out[OFF_WORD + n] = (float)ow;
    bool cpym = (c0 == 1.0f) && (msk != 0);
    out[OFF_CPYM + n] = cpym ? 1.f : 0.f;
    out[OFF_OBFM + n] = (isobf && !cpym) ? 1.f : 0.f;
    out[OFF_PRIM + n] = ispri ? 1.f : 0.f;
    #pragma unroll
    for (int j = 0; j < CLEN; ++j)
      out[OFF_CHAR + (size_t)n*CLEN + j] = (float)lut[(size_t)ow*CLEN + j];
  }
  if (t < DD){
    float po = psr_w[(size_t)word*DD + t];
    float pb = isobf ? psr_w[(size_t)obf_word*DD + t] : po;
    out[OFF_PSR + (size_t)n*DD + t] = __fadd_rn(__fmul_rn(po, c0), __fmul_rn(pb, c1));
    float ao = atk_w[(size_t)word*DD + t];
    float ab = isobf ? atk_w[(size_t)obf_word*DD + t] : ao;
    out[OFF_ATK + (size_t)n*DD + t] = __fadd_rn(__fmul_rn(ao, c0), __fmul_rn(ab, c1));
  }
}

extern "C" void kernel_launch(void* const* d_in, const int* in_sizes, int n_in,
                              void* d_out, int out_size, void* d_ws, size_t ws_size,
                              hipStream_t stream)
{
  const float* ctx      = (const float*)d_in[0];
  const float* dec_W    = (const float*)d_in[1];
  const float* dec_b    = (const float*)d_in[2];
  const float* psr_w    = (const float*)d_in[3];
  const float* atk_w    = (const float*)d_in[4];
  const float* cW1      = (const float*)d_in[5];
  const float* cb1      = (const float*)d_in[6];
  const float* cW2      = (const float*)d_in[7];
  const float* cb2      = (const float*)d_in[8];
  const int*   inp_word = (const int*)d_in[9];
  const int*   inp_pos  = (const int*)d_in[10];
  const int*   inp_mask = (const int*)d_in[11];
  const int*   words    = (const int*)d_in[12];
  const int*   lut      = (const int*)d_in[13];
  float* out = (float*)d_out;
  float* ws  = (float*)d_ws;

  const size_t need = ((size_t)WS_LOGITS_OFF + (size_t)NTOT*MM) * 4;

  hipMemsetAsync(ws, 0, 512, stream);   // ent/closs floats + cnt ints

  if (ws_size >= need){
    int*   cntg      = (int*)ws + 16;
    int*   rowlist   = (int*)ws + 64;
    float* scbuf     = ws + WS_SC_OFF;
    float* logitsbuf = ws + WS_LOGITS_OFF;
    cpy_build_kernel<<<NTOT/CPB, 256, 0, stream>>>(ctx, cW1, cb1, cW2, cb2,
                                                   inp_pos, inp_mask, cntg, rowlist,
                                                   scbuf, ws);
    gemm_kernel<<<dim3(MM/CT, LISTCAP/RT, PP), 256, 0, stream>>>(ctx, dec_W, cntg,
                                                                 rowlist, logitsbuf);
    finalize_kernel<<<NTOT/4, 256, 0, stream>>>(dec_b, psr_w, atk_w,
                                                inp_word, inp_pos, inp_mask, words, lut,
                                                logitsbuf, scbuf, out, ws);
  } else {
    row_kernel_mono<<<NTOT, 256, 0, stream>>>(ctx, dec_W, dec_b, psr_w, atk_w,
                                              cW1, cb1, cW2, cb2,
                                              inp_word, inp_pos, inp_mask, words, lut,
                                              out, ws);
  }
  fin_kernel<<<1, 256, 0, stream>>>(inp_pos, inp_mask, ws, out);
}